// Round 1
// baseline (364.495 us; speedup 1.0000x reference)
//
#include <hip/hip_runtime.h>

#define N_NODES 100000
#define D 128

typedef unsigned short u16;
typedef short s16x8 __attribute__((ext_vector_type(8)));
typedef float f32x4 __attribute__((ext_vector_type(4)));

// ---------------- ws layout ----------------
// ints (4B):
//   deg    @ 0        (300000)   per-type in-degree [type*100000 + d]
//   offs   @ 300000   (100001)   unified entry-list exclusive scan (+sentinel)
//   cursor @ 400001   (300000)   per-(type,dest) segment cursors
//   bsums  @ 700001   (512)
//   boffs  @ 700513   (512)
// int  ents @ byte 2804224  (1,600,000 x 4B = 6.4 MB)  src node index only
// u16  ATb  @ byte 9204224  (7 x 16384 = 229 KB)  transposed bf16 weights [slot][n][k]
// u16  G    @ byte 9433600  (100000 x 7 x 128 = 179.2 MB)  bf16 aggregated slots
//   slot 0 = r1 agg, 1..2 = r2 agg, 3..5 = r3 agg, 6 = x (bf16)
// total ~188.7 MB

#define ENTS_OFF 2804224L
#define AT_OFF   9204224L
#define G_OFF    9433600L

__device__ __forceinline__ u16 f2b(float f) {
    union { float f; unsigned u; } v; v.f = f;
    unsigned r = (v.u + 0x7FFFu + ((v.u >> 16) & 1u)) >> 16;
    return (u16)r;
}
__device__ __forceinline__ unsigned pk(float lo, float hi) {
    return (unsigned)f2b(lo) | ((unsigned)f2b(hi) << 16);
}
__device__ __forceinline__ float blo(unsigned w) { return __uint_as_float(w << 16); }
__device__ __forceinline__ float bhi(unsigned w) { return __uint_as_float(w & 0xFFFF0000u); }

// ---------------- K1: zero deg + transpose/convert weights + x -> G slot 6 ----------------
// blocks [0,293): zero deg. [293,741): ATb (7 mats x 64 blocks). [741,6991): x -> bf16.

__global__ __launch_bounds__(256) void init_kernel(
    const float* __restrict__ x,
    const float* __restrict__ A1, const float* __restrict__ A2,
    const float* __restrict__ A3, const float* __restrict__ Cw,
    u16* __restrict__ ATb, u16* __restrict__ G, int* __restrict__ deg) {
    int b = blockIdx.x, t = threadIdx.x;
    if (b < 293) {
        int i0 = (b * 256 + t) * 4;
#pragma unroll
        for (int r = 0; r < 4; r++)
            if (i0 + r < 300000) deg[i0 + r] = 0;
        return;
    }
    if (b < 741) {
        int mb = b - 293;
        int m = mb >> 6;
        int idx = (mb & 63) * 256 + t;  // 0..16383
        int n = idx >> 7, kk = idx & 127;
        const float* src; int srow;
        if (m == 0)      { src = A1; srow = kk; }
        else if (m < 3)  { src = A2; srow = (m - 1) * 128 + kk; }
        else if (m < 6)  { src = A3; srow = (m - 3) * 128 + kk; }
        else             { src = Cw; srow = kk; }
        ATb[m * 16384 + n * 128 + kk] = f2b(src[(long)srow * 128 + n]);
        return;
    }
    // x conversion: 100000 rows x 128 cols, 16 threads/row, 8 elems/thread
    int f = (b - 741) * 256 + t;          // 0..1,599,999 exact
    int node = f >> 4, j = f & 15;
    const float* xr = x + (long)node * 128 + j * 8;
    float4 v0 = *(const float4*)xr;
    float4 v1 = *(const float4*)(xr + 4);
    uint4 o;
    o.x = pk(v0.x, v0.y); o.y = pk(v0.z, v0.w);
    o.z = pk(v1.x, v1.y); o.w = pk(v1.z, v1.w);
    *(uint4*)(G + (long)node * 896 + 768 + j * 8) = o;
}

// ---------------- K2: per-type in-degree ----------------

__global__ __launch_bounds__(256) void deg_all(
    const int* __restrict__ e1, const int* __restrict__ e2, const int* __restrict__ e3,
    int ne1, int ne2, int ne3, int* __restrict__ deg) {
    int g = blockIdx.x * 256 + threadIdx.x;
    if (g < ne1) {
        atomicAdd(&deg[e1[ne1 + g]], 1);
    } else if (g < ne1 + ne2) {
        int e = g - ne1;
        atomicAdd(&deg[N_NODES + e2[ne2 * 2 + e * 2]], 1);
    } else if (g < ne1 + ne2 + ne3) {
        int e = g - ne1 - ne2;
        atomicAdd(&deg[2 * N_NODES + e3[ne3 * 3 + e * 3]], 1);
    }
}

// unified per-dest entry count: u[d] = c1 + 2*c2 + 3*c3  (no self entry anymore)
__device__ __forceinline__ int ucnt(const int* deg, int d) {
    return deg[d] + 2 * deg[N_NODES + d] + 3 * deg[2 * N_NODES + d];
}

// ---------------- K3..K5: exclusive scan of ucnt over 100000 ----------------

__global__ __launch_bounds__(256) void scan_reduce_u(const int* __restrict__ deg,
                                                     int* __restrict__ bsums, int n) {
    __shared__ int s[256];
    int t = threadIdx.x;
    int base = blockIdx.x * 1024 + t * 4;
    int loc = 0;
#pragma unroll
    for (int r = 0; r < 4; r++) {
        int idx = base + r;
        if (idx < n) loc += ucnt(deg, idx);
    }
    s[t] = loc;
    for (int off = 128; off > 0; off >>= 1) {
        __syncthreads();
        if (t < off) s[t] += s[t + off];
    }
    if (t == 0) bsums[blockIdx.x] = s[0];
}

__global__ __launch_bounds__(512) void scan_tops(const int* __restrict__ bsums,
                                                 int* __restrict__ boffs,
                                                 int* __restrict__ offs, int nb, int n) {
    __shared__ int s[512];
    int t = threadIdx.x;
    int v = (t < nb) ? bsums[t] : 0;
    s[t] = v;
    for (int off = 1; off < 512; off <<= 1) {
        __syncthreads();
        int x = (t >= off) ? s[t - off] : 0;
        __syncthreads();
        s[t] += x;
    }
    if (t < nb) boffs[t] = s[t] - v;
    if (t == nb - 1) offs[n] = s[t];
}

// final scan; seeds 3 per-type cursors at each dest's slot-segment bases
__global__ __launch_bounds__(256) void scan_final_u(
    const int* __restrict__ deg, const int* __restrict__ boffs,
    int* __restrict__ offs, int* __restrict__ cursor, int n) {
    __shared__ int s[256];
    int t = threadIdx.x;
    int base = blockIdx.x * 1024 + t * 4;
    int v[4], p[4];
#pragma unroll
    for (int r = 0; r < 4; r++) {
        int idx = base + r;
        v[r] = (idx < n) ? ucnt(deg, idx) : 0;
    }
    p[0] = 0; p[1] = v[0]; p[2] = v[0] + v[1]; p[3] = v[0] + v[1] + v[2];
    int tsum = p[3] + v[3];
    s[t] = tsum;
    for (int off = 1; off < 256; off <<= 1) {
        __syncthreads();
        int x = (t >= off) ? s[t - off] : 0;
        __syncthreads();
        s[t] += x;
    }
    int texcl = s[t] - tsum + boffs[blockIdx.x];
#pragma unroll
    for (int r = 0; r < 4; r++) {
        int idx = base + r;
        if (idx < n) {
            int val = texcl + p[r];
            offs[idx] = val;
            int c1 = deg[idx], c2 = deg[N_NODES + idx];
            cursor[idx] = val;                                // r1 segment
            cursor[N_NODES + idx] = val + c1;                 // r2 slot-1 segment
            cursor[2 * N_NODES + idx] = val + c1 + 2 * c2;    // r3 slot-3 segment
        }
    }
}

// ---------------- K6: scatter src indices into slot-segmented entry list ----------------
// dest range layout: [c1 slot0][c2 slot1][c2 slot2][c3 slot3][c3 slot4][c3 slot5]

__global__ __launch_bounds__(256) void scatter_all(
    const int* __restrict__ e1, const int* __restrict__ e2, const int* __restrict__ e3,
    int ne1, int ne2, int ne3, const int* __restrict__ deg,
    int* __restrict__ cursor, int* __restrict__ ents) {
    int g = blockIdx.x * 256 + threadIdx.x;
    if (g < ne1) {
        int dest = e1[ne1 + g];
        int pos = atomicAdd(&cursor[dest], 1);
        ents[pos] = e1[g];
    } else if (g < ne1 + ne2) {
        int e = g - ne1;
        int dest = e2[ne2 * 2 + e * 2];
        int c2 = deg[N_NODES + dest];
        int pos = atomicAdd(&cursor[N_NODES + dest], 1);
        ents[pos]      = e2[e * 2];
        ents[pos + c2] = e2[e * 2 + 1];
    } else if (g < ne1 + ne2 + ne3) {
        int e = g - ne1 - ne2;
        int dest = e3[ne3 * 3 + e * 3];
        int c3 = deg[2 * N_NODES + dest];
        int pos = atomicAdd(&cursor[2 * N_NODES + dest], 1);
        ents[pos]          = e3[e * 3];
        ents[pos + c3]     = e3[e * 3 + 1];
        ents[pos + 2 * c3] = e3[e * 3 + 2];
    }
}

// ---------------- K7: aggregate — G[d][slot] = (1/c_t) * sum x_bf16[src] ----------------
// One wave per dest (grid-stride). Reads bf16 x rows from G slot 6 (25.6 MB, L3-hot).

__global__ __launch_bounds__(256) void agg_all(
    u16* __restrict__ G, const int* __restrict__ ents,
    const int* __restrict__ offs, const int* __restrict__ deg) {
    const int lane = threadIdx.x & 63;
    const int wv = threadIdx.x >> 6;
    int wid = blockIdx.x * 4 + wv;
    const int nw = gridDim.x * 4;
    const int col = lane * 2;

    for (int d = wid; d < N_NODES; d += nw) {
        const int lo = offs[d];
        const int c1 = deg[d], c2 = deg[N_NODES + d], c3 = deg[2 * N_NODES + d];
        float a0l = 0, a0h = 0, a1l = 0, a1h = 0, a2l = 0, a2h = 0;
        float a3l = 0, a3h = 0, a4l = 0, a4h = 0, a5l = 0, a5h = 0;

        for (int p = 0; p < c1; p += 4) {
            unsigned w[4]; float m[4];
#pragma unroll
            for (int i = 0; i < 4; i++) {
                int q = (p + i < c1) ? p + i : c1 - 1;
                int src = ents[lo + q];
                w[i] = *(const unsigned*)(G + (long)src * 896 + 768 + col);
                m[i] = (p + i < c1) ? 1.0f : 0.0f;
            }
#pragma unroll
            for (int i = 0; i < 4; i++) {
                a0l = fmaf(m[i], blo(w[i]), a0l);
                a0h = fmaf(m[i], bhi(w[i]), a0h);
            }
        }
        const int o1 = lo + c1;
        for (int p = 0; p < c2; p += 4) {
            unsigned wa[4], wb[4]; float m[4];
#pragma unroll
            for (int i = 0; i < 4; i++) {
                int q = (p + i < c2) ? p + i : c2 - 1;
                int sa = ents[o1 + q];
                int sb = ents[o1 + q + c2];
                wa[i] = *(const unsigned*)(G + (long)sa * 896 + 768 + col);
                wb[i] = *(const unsigned*)(G + (long)sb * 896 + 768 + col);
                m[i] = (p + i < c2) ? 1.0f : 0.0f;
            }
#pragma unroll
            for (int i = 0; i < 4; i++) {
                a1l = fmaf(m[i], blo(wa[i]), a1l); a1h = fmaf(m[i], bhi(wa[i]), a1h);
                a2l = fmaf(m[i], blo(wb[i]), a2l); a2h = fmaf(m[i], bhi(wb[i]), a2h);
            }
        }
        const int o3 = o1 + 2 * c2;
        for (int p = 0; p < c3; p += 4) {
            unsigned wa[4], wb[4], wc[4]; float m[4];
#pragma unroll
            for (int i = 0; i < 4; i++) {
                int q = (p + i < c3) ? p + i : c3 - 1;
                int sa = ents[o3 + q];
                int sb = ents[o3 + q + c3];
                int sc = ents[o3 + q + 2 * c3];
                wa[i] = *(const unsigned*)(G + (long)sa * 896 + 768 + col);
                wb[i] = *(const unsigned*)(G + (long)sb * 896 + 768 + col);
                wc[i] = *(const unsigned*)(G + (long)sc * 896 + 768 + col);
                m[i] = (p + i < c3) ? 1.0f : 0.0f;
            }
#pragma unroll
            for (int i = 0; i < 4; i++) {
                a3l = fmaf(m[i], blo(wa[i]), a3l); a3h = fmaf(m[i], bhi(wa[i]), a3h);
                a4l = fmaf(m[i], blo(wb[i]), a4l); a4h = fmaf(m[i], bhi(wb[i]), a4h);
                a5l = fmaf(m[i], blo(wc[i]), a5l); a5h = fmaf(m[i], bhi(wc[i]), a5h);
            }
        }
        const float i1 = c1 ? 1.0f / (float)c1 : 0.0f;
        const float i2 = c2 ? 1.0f / (float)c2 : 0.0f;
        const float i3 = c3 ? 1.0f / (float)c3 : 0.0f;
        u16* gd = G + (long)d * 896 + col;
        *(unsigned*)(gd)       = pk(a0l * i1, a0h * i1);
        *(unsigned*)(gd + 128) = pk(a1l * i2, a1h * i2);
        *(unsigned*)(gd + 256) = pk(a2l * i2, a2h * i2);
        *(unsigned*)(gd + 384) = pk(a3l * i3, a3h * i3);
        *(unsigned*)(gd + 512) = pk(a4l * i3, a4h * i3);
        *(unsigned*)(gd + 640) = pk(a5l * i3, a5h * i3);
    }
}

// ---------------- K8: out = G @ Acat + Cb  (K = 896, one 64-row tile per block) ----------
// K-accumulating variant of the proven gemm_all structure: stage 64x128 bf16 chunk per
// slot into padded LDS, MFMA-accumulate across 7 slots, single LDS-bounce fp32 epilogue.
// MFMA C layout: col=lane&15, row=quad*4+reg.

__global__ __launch_bounds__(256) void gemm_out(
    const u16* __restrict__ G, const u16* __restrict__ AT,
    const float* __restrict__ Cb, float* __restrict__ out) {
    __shared__ __align__(16) float smemf[64 * 132];  // 33792 B; first 20480 B aliased as Xs
    typedef u16 XsT[64][40];
    XsT* Xs = reinterpret_cast<XsT*>(smemf);

    const int t = threadIdx.x;
    const int d0 = blockIdx.x * 64;
    const int lane = t & 63, wv = t >> 6;
    const int nbase = wv * 32, quad = lane >> 4, lrow = lane & 15;

    f32x4 acc[4][2];
#pragma unroll
    for (int mi = 0; mi < 4; mi++)
#pragma unroll
        for (int ni = 0; ni < 2; ni++) acc[mi][ni] = (f32x4)(0.0f);

    for (int s = 0; s < 7; s++) {
        // stage 64 rows x 128 k of slot s (pure bf16 copy, 16B per thread-iter)
#pragma unroll
        for (int i = 0; i < 4; i++) {
            int f = i * 256 + t;
            int row = f >> 4, k8 = f & 15;
            long rs = (d0 + row < N_NODES) ? d0 + row : N_NODES - 1;
            uint4 v = *(const uint4*)(G + rs * 896 + s * 128 + k8 * 8);
            *(uint4*)&Xs[k8 >> 2][row][(k8 & 3) * 8] = v;
        }
        __syncthreads();
        const u16* B = AT + s * 16384;
        s16x8 bfrag[2][4];
#pragma unroll
        for (int ni = 0; ni < 2; ni++)
#pragma unroll
            for (int c = 0; c < 4; c++)
                bfrag[ni][c] = *(const s16x8*)(B + (nbase + ni * 16 + lrow) * 128 +
                                               c * 32 + quad * 8);
        s16x8 afrag[4][4];
#pragma unroll
        for (int mi = 0; mi < 4; mi++)
#pragma unroll
            for (int c = 0; c < 4; c++)
                afrag[mi][c] = *(const s16x8*)&Xs[c][mi * 16 + lrow][quad * 8];
#pragma unroll
        for (int c = 0; c < 4; c++)
#pragma unroll
            for (int mi = 0; mi < 4; mi++)
#pragma unroll
                for (int ni = 0; ni < 2; ni++)
                    acc[mi][ni] = __builtin_amdgcn_mfma_f32_16x16x32_bf16(
                        afrag[mi][c], bfrag[ni][c], acc[mi][ni], 0, 0, 0);
        __syncthreads();  // all afrag reads done before next stage overwrites Xs
    }

    // epilogue: bounce through LDS for coalesced float4 stores, add Cb
#pragma unroll
    for (int mi = 0; mi < 4; mi++)
#pragma unroll
        for (int ni = 0; ni < 2; ni++)
#pragma unroll
            for (int reg = 0; reg < 4; reg++) {
                int row = mi * 16 + quad * 4 + reg;
                int colq = nbase + ni * 16 + lrow;
                smemf[row * 132 + colq] = acc[mi][ni][reg];
            }
    __syncthreads();
#pragma unroll
    for (int i = 0; i < 8; i++) {
        int f = i * 256 + t;
        int row = f >> 5;
        int colq = (f & 31) * 4;
        if (d0 + row < N_NODES) {
            float4 v = *(const float4*)&smemf[row * 132 + colq];
            float4 b = *(const float4*)&Cb[colq];
            v.x += b.x; v.y += b.y; v.z += b.z; v.w += b.w;
            *(float4*)&out[(long)(d0 + row) * 128 + colq] = v;
        }
    }
}

// ---------------- launcher ----------------

extern "C" void kernel_launch(void* const* d_in, const int* in_sizes, int n_in,
                              void* d_out, int out_size, void* d_ws, size_t ws_size,
                              hipStream_t stream) {
    const float* x  = (const float*)d_in[0];
    const float* A1 = (const float*)d_in[1];
    const float* A2 = (const float*)d_in[2];
    const float* A3 = (const float*)d_in[3];
    const float* Cw = (const float*)d_in[4];
    const float* Cb = (const float*)d_in[5];
    const int* e1 = (const int*)d_in[6];
    const int* e2 = (const int*)d_in[7];
    const int* e3 = (const int*)d_in[8];
    float* out = (float*)d_out;

    int* ws = (int*)d_ws;
    int* deg    = ws;
    int* offs   = ws + 300000;
    int* cursor = ws + 400001;
    int* bsums  = ws + 700001;
    int* boffs  = ws + 700513;
    int* ents   = (int*)((char*)d_ws + ENTS_OFF);
    u16* ATb    = (u16*)((char*)d_ws + AT_OFF);
    u16* G      = (u16*)((char*)d_ws + G_OFF);

    const int NE1 = in_sizes[6] / 2;        // 400000
    const int NE2 = in_sizes[7] / (2 * 2);  // 300000
    const int NE3 = in_sizes[8] / (2 * 3);  // 200000
    const int NET = NE1 + NE2 + NE3;        // 900000
    const int n = N_NODES;
    const int NB = (n + 1023) / 1024;       // 98

    init_kernel<<<293 + 448 + 6250, 256, 0, stream>>>(x, A1, A2, A3, Cw, ATb, G, deg);
    deg_all<<<(NET + 255) / 256, 256, 0, stream>>>(e1, e2, e3, NE1, NE2, NE3, deg);
    scan_reduce_u<<<NB, 256, 0, stream>>>(deg, bsums, n);
    scan_tops<<<1, 512, 0, stream>>>(bsums, boffs, offs, NB, n);
    scan_final_u<<<NB, 256, 0, stream>>>(deg, boffs, offs, cursor, n);
    scatter_all<<<(NET + 255) / 256, 256, 0, stream>>>(e1, e2, e3, NE1, NE2, NE3,
                                                       deg, cursor, ents);
    agg_all<<<2048, 256, 0, stream>>>(G, ents, offs, deg);
    gemm_out<<<(N_NODES + 63) / 64, 256, 0, stream>>>(G, ATb, Cb, out);
}